// Round 7
// baseline (430.028 us; speedup 1.0000x reference)
//
#include <hip/hip_runtime.h>

// ---------------------------------------------------------------------------
// StyleGAN2-like generator forward. Convs via bf16 MFMA implicit GEMM,
// A+B staged via global_load_lds DMA with coalesced sources (R5).
// R7: fixes R6's wbconv_all enumeration bug — (c,kv) has 64 combos, not 16
//   (ckv = rr & 63, grid 896 blocks = 7*64*512 threads). R6 only repacked
//   input channels 0..127; the rest of wbuf7/wsq7 were stale (absmax 3.5).
//   Coalesced design unchanged: 288B contiguous read/thread, 9 x 16B uint4
//   writes forming 1KB wave segments matching the conv DMA source layout.
// B=8, C=512, output [8,3,32,32] f32.
// ---------------------------------------------------------------------------

#define SQRT2F      1.41421356f
#define MAP_SCALE   4.41941738e-04f   // 0.01/sqrt(512)
#define MOD_SCALE   4.41941738e-02f   // 1/sqrt(512)
#define CONV_SCALE  1.47313913e-02f   // 1/sqrt(512*9)
#define RGB_SCALE   4.41941738e-02f   // 1/sqrt(512)

typedef __attribute__((ext_vector_type(8))) short bf16x8;
typedef __attribute__((ext_vector_type(16))) float f32x16;

__device__ __forceinline__ float bf2f(ushort u) {
    return __uint_as_float(((unsigned)u) << 16);
}
__device__ __forceinline__ ushort f2bf(float f) {
    unsigned u = __float_as_uint(f);
    unsigned r = (u + 0x7FFFu + ((u >> 16) & 1u)) >> 16;
    return (ushort)r;
}
__device__ __forceinline__ void store4bf(ushort* p, float a, float b, float c, float d) {
    union { ushort u[4]; uint2 v; } x;
    x.u[0] = f2bf(a); x.u[1] = f2bf(b); x.u[2] = f2bf(c); x.u[3] = f2bf(d);
    *(uint2*)p = x.v;
}

// direct global->LDS DMA, 16B per lane. LDS dest wave-uniform base + lane*16;
// global source is per-lane.
typedef __attribute__((address_space(1))) const unsigned int GAS;
typedef __attribute__((address_space(3))) unsigned int LAS;
__device__ __forceinline__ void gload_lds16(const ushort* g, ushort* l) {
    __builtin_amdgcn_global_load_lds((GAS*)g, (LAS*)l, 16, 0, 0);
}

// ============================ PRNG (JAX threefry) ===========================

__device__ __forceinline__ unsigned rotl32(unsigned x, int r) {
    return (x << r) | (x >> (32 - r));
}

__device__ void threefry2x32(unsigned k0, unsigned k1, unsigned x0, unsigned x1,
                             unsigned& o0, unsigned& o1) {
    unsigned k2 = k0 ^ k1 ^ 0x1BD11BDAu;
    x0 += k0; x1 += k1;
    x0 += x1; x1 = rotl32(x1,13); x1 ^= x0;
    x0 += x1; x1 = rotl32(x1,15); x1 ^= x0;
    x0 += x1; x1 = rotl32(x1,26); x1 ^= x0;
    x0 += x1; x1 = rotl32(x1, 6); x1 ^= x0;
    x0 += k1; x1 += k2 + 1u;
    x0 += x1; x1 = rotl32(x1,17); x1 ^= x0;
    x0 += x1; x1 = rotl32(x1,29); x1 ^= x0;
    x0 += x1; x1 = rotl32(x1,16); x1 ^= x0;
    x0 += x1; x1 = rotl32(x1,24); x1 ^= x0;
    x0 += k2; x1 += k0 + 2u;
    x0 += x1; x1 = rotl32(x1,13); x1 ^= x0;
    x0 += x1; x1 = rotl32(x1,15); x1 ^= x0;
    x0 += x1; x1 = rotl32(x1,26); x1 ^= x0;
    x0 += x1; x1 = rotl32(x1, 6); x1 ^= x0;
    x0 += k0; x1 += k1 + 3u;
    x0 += x1; x1 = rotl32(x1,17); x1 ^= x0;
    x0 += x1; x1 = rotl32(x1,29); x1 ^= x0;
    x0 += x1; x1 = rotl32(x1,16); x1 ^= x0;
    x0 += x1; x1 = rotl32(x1,24); x1 ^= x0;
    x0 += k1; x1 += k2 + 4u;
    x0 += x1; x1 = rotl32(x1,13); x1 ^= x0;
    x0 += x1; x1 = rotl32(x1,15); x1 ^= x0;
    x0 += x1; x1 = rotl32(x1,26); x1 ^= x0;
    x0 += x1; x1 = rotl32(x1, 6); x1 ^= x0;
    x0 += k2; x1 += k0 + 5u;
    o0 = x0; o1 = x1;
}

__device__ float bits_to_normal(unsigned bits) {
    unsigned m = (bits >> 9) | 0x3F800000u;
    float f = __uint_as_float(m) - 1.0f;
    const float lo = -0.99999994f;
    float u = f * 2.0f + lo;
    u = fmaxf(lo, u);
    float w = -log1pf(-u * u);
    float p;
    if (w < 5.0f) {
        w -= 2.5f;
        p = 2.81022636e-08f;
        p = fmaf(p, w, 3.43273939e-07f);
        p = fmaf(p, w, -3.5233877e-06f);
        p = fmaf(p, w, -4.39150654e-06f);
        p = fmaf(p, w, 0.00021858087f);
        p = fmaf(p, w, -0.00125372503f);
        p = fmaf(p, w, -0.00417768164f);
        p = fmaf(p, w, 0.246640727f);
        p = fmaf(p, w, 1.50140941f);
    } else {
        w = sqrtf(w) - 3.0f;
        p = -0.000200214257f;
        p = fmaf(p, w, 0.000100950558f);
        p = fmaf(p, w, 0.00134934322f);
        p = fmaf(p, w, -0.00367342844f);
        p = fmaf(p, w, 0.00573950773f);
        p = fmaf(p, w, -0.0076224613f);
        p = fmaf(p, w, 0.00943887047f);
        p = fmaf(p, w, 1.00167406f);
        p = fmaf(p, w, 2.83297682f);
    }
    return 1.41421354f * (p * u);
}

__global__ void noise_kernel(float* __restrict__ nbuf) {
    int g = blockIdx.x * 256 + threadIdx.x;
    if (g >= 21632) return;
    const int off[8] = {0, 128, 640, 1152, 3200, 5248, 13440, 21632};
    int l = 0;
    while (l < 6 && g >= off[l + 1]) l++;
    int i = g - off[l];
    unsigned k0, k1;
    threefry2x32(0u, 7u, 0u, (unsigned)l, k0, k1);
    unsigned b0, b1;
    threefry2x32(k0, k1, 0u, (unsigned)i, b0, b1);
    nbuf[g] = bits_to_normal(b0 ^ b1);
}

// ============================ small linear kernels ==========================

__global__ void pixelnorm_kernel(const float* __restrict__ z, float* __restrict__ out) {
    int b = blockIdx.x;
    int lane = threadIdx.x;
    float v[8];
    float s = 0.f;
    #pragma unroll
    for (int j = 0; j < 8; j++) {
        v[j] = z[b * 512 + lane + (j << 6)];
        s += v[j] * v[j];
    }
    #pragma unroll
    for (int off = 32; off > 0; off >>= 1) s += __shfl_xor(s, off, 64);
    float norm = rsqrtf(s * (1.f / 512.f) + 1e-8f);
    #pragma unroll
    for (int j = 0; j < 8; j++)
        out[b * 512 + lane + (j << 6)] = v[j] * norm;
}

__global__ void dot512_kernel(const float* __restrict__ win, const float* __restrict__ W,
                              const float* __restrict__ bias, float* __restrict__ out,
                              int total, float wscale, float bscale, int mode) {
    int gt = blockIdx.x * blockDim.x + threadIdx.x;
    int wv = gt >> 6;
    int lane = gt & 63;
    if (wv >= total) return;
    int l = wv >> 12;
    int r = wv & 4095;
    int b = r >> 9;
    int o = r & 511;
    const float* wrow = W + ((size_t)(l * 512 + o) << 9);
    const float* xrow = win + ((size_t)b << 9);
    float s = 0.f;
    #pragma unroll
    for (int j = 0; j < 8; j++) {
        int k = lane + (j << 6);
        s += wrow[k] * xrow[k];
    }
    #pragma unroll
    for (int off = 32; off > 0; off >>= 1) s += __shfl_xor(s, off, 64);
    if (lane == 0) {
        float v = s * wscale + bias[l * 512 + o] * bscale;
        if (mode) v = (v > 0.f ? v : 0.2f * v) * SQRT2F;
        out[wv] = v;
    }
}

// weight repack to coalesced-DMA layout: wb[l][c][t][kv][o][8e]
// (i = c*32+kv*8+e). flip taps for l=1,3,5. + wsq7[l][o][i].
// thread = (l,c,kv,o), o fastest -> coalesced 16B writes, 288B reads.
__global__ void wbconv_all(const float* __restrict__ cw, ushort* __restrict__ wb7,
                           float* __restrict__ wsq7) {
    int gid = blockIdx.x * 256 + threadIdx.x;
    if (gid >= 229376) return;                   // 7*64*512
    int o = gid & 511;
    int rr = gid >> 9;                           // l*64 + ckv
    int l = rr >> 6, ckv = rr & 63;
    int c = ckv >> 2, kv = ckv & 3;
    int ibase = c * 32 + kv * 8;
    int flip = (l == 1 || l == 3 || l == 5);
    const float* src = cw + ((size_t)(l * 512 + o) * 512 + ibase) * 9;
    float w[72];
    #pragma unroll
    for (int q = 0; q < 18; q++) {
        float4 v = *(const float4*)(src + q * 4);
        w[q * 4 + 0] = v.x; w[q * 4 + 1] = v.y;
        w[q * 4 + 2] = v.z; w[q * 4 + 3] = v.w;
    }
    float* wq = wsq7 + (size_t)(l * 512 + o) * 512 + ibase;
    float s[8];
    #pragma unroll
    for (int e = 0; e < 8; e++) {
        float a = 0.f;
        #pragma unroll
        for (int t = 0; t < 9; t++) { float x = w[e * 9 + t]; a += x * x; }
        s[e] = a;
    }
    *(float4*)wq = make_float4(s[0], s[1], s[2], s[3]);
    *(float4*)(wq + 4) = make_float4(s[4], s[5], s[6], s[7]);
    ushort* wb = wb7 + (size_t)l * 2359296;
    #pragma unroll
    for (int t = 0; t < 9; t++) {
        int tsrc = flip ? (8 - t) : t;
        union { ushort u[8]; uint4 v; } pk;
        #pragma unroll
        for (int e = 0; e < 8; e++) pk.u[e] = f2bf(w[e * 9 + tsrc]);
        *(uint4*)&wb[(size_t)(((c * 9 + t) * 4 + kv) * 512 + o) * 8] = pk.v;
    }
}

// all-layer demod: dm[l][b][o]
__global__ void demod_all(const float* __restrict__ wsq7, const float* __restrict__ sc,
                          float* __restrict__ dm) {
    int gt = blockIdx.x * blockDim.x + threadIdx.x;
    int wv = gt >> 6;
    int lane = gt & 63;
    if (wv >= 7 * 4096) return;
    int l = wv >> 12, b = (wv >> 9) & 7, o = wv & 511;
    const float* wr = wsq7 + (size_t)l * 262144 + ((size_t)o << 9);
    const float* sr = sc + l * 4096 + (b << 9);
    float s = 0.f;
    #pragma unroll
    for (int j = 0; j < 8; j++) {
        int k = lane + (j << 6);
        float sv = sr[k];
        s += wr[k] * sv * sv;
    }
    #pragma unroll
    for (int off = 32; off > 0; off >>= 1) s += __shfl_xor(s, off, 64);
    if (lane == 0) dm[wv] = rsqrtf(s * (1.f / 4608.f) + 1e-8f);
}

// prep l0 input, g-major: X0p[g=ch/8][px(288)][8] = styled padded const_input
__global__ void prep0_kernel(const float* __restrict__ cinp, const float* __restrict__ s0,
                             ushort* __restrict__ X0p) {
    int gid = blockIdx.x * 256 + threadIdx.x;
    if (gid >= 8 * 36 * 64) return;
    int grp = gid & 63;
    int r = gid >> 6;             // px index 0..287 (b*36 + row*6 + col)
    int b = r / 36, rc = r % 36, row = rc / 6, col = rc % 6;
    int y = row - 1, x = col - 1;
    union { ushort u[8]; bf16x8 v; } pk;
    if (y >= 0 && y < 4 && x >= 0 && x < 4) {
        #pragma unroll
        for (int k = 0; k < 8; k++) {
            int ch = grp * 8 + k;
            pk.u[k] = f2bf(cinp[ch * 16 + y * 4 + x] * s0[b * 512 + ch]);
        }
    } else {
        #pragma unroll
        for (int k = 0; k < 8; k++) pk.u[k] = 0;
    }
    *(bf16x8*)&X0p[((size_t)grp * 288 + r) * 8] = pk.v;
}

// ==== dense conv v5: coalesced DMA staging + dbuf + counted vmcnt ==========
// A LDS [tap][kv][o] <- wb[l][c][t][kv][o][8] (contiguous). B LDS [kv][px]
// <- Xg[g=c*4+kv][px][8] (contiguous per kv run). MFMA reads conflict-free.
template <int S, int NTILE, int WROWS, int KS, bool WUP>
__global__ __launch_bounds__(256, 2) void conv_dense5(
    const ushort* __restrict__ Xp, const ushort* __restrict__ wb,
    const float* __restrict__ dm, const float* __restrict__ nz,
    const float* __restrict__ nstr, const float* __restrict__ bias,
    const float* __restrict__ snext,
    ushort* __restrict__ T, ushort* __restrict__ XU, float* __restrict__ Pp) {
    constexpr int SP = S + 2, P2 = S * S, N = 8 * P2;
    constexpr int PXT = 8 * SP * SP;             // total padded px
    constexpr int JCOLS = NTILE / 128;
    constexpr int NPX = WROWS * SP;
    constexpr int ASZ = 9 * 4 * 64 * 8;          // 18432 us per chunk
    constexpr int BSZ = NPX * 32;                // us per chunk
    constexpr int PAIR = ASZ + BSZ;
    constexpr int NBU = NPX * 4;                 // 16B units of B per chunk
    constexpr int NBT = (NBU + 255) / 256;
    constexpr int ROWMAX = 8 * SP - 1;
    constexpr int CK = 16 / KS;
    constexpr int DB = (CK > 1) ? 2 : 1;
    constexpr int MINB = (NBU > 192) ? ((NBU - 192 + 255) / 256) : 0;
    constexpr int NMIN = 9 + MINB;
    __shared__ __align__(16) ushort lds[DB * PAIR];

    const int tid = threadIdx.x, lane = tid & 63, nw = tid >> 6;
    const int hf = lane >> 5, l31 = lane & 31;
    const int o0 = blockIdx.x * 64;
    const int n0 = blockIdx.y * NTILE;
    const int ks = blockIdx.z;
    const int R0 = (n0 / P2) * SP + (n0 % P2) / S;

    int pixbase[JCOLS], nj[JCOLS];
    #pragma unroll
    for (int j = 0; j < JCOLS; j++) {
        int n = n0 + nw * (NTILE / 4) + j * 32 + l31;
        nj[j] = n;
        int b = n / P2, r = n % P2;
        int y = r / S, x = r % S;
        pixbase[j] = (b * SP + y - R0) * SP + x;   // px units
    }
    f32x16 acc[JCOLS][2];
    #pragma unroll
    for (int j = 0; j < JCOLS; j++) { acc[j][0] = (f32x16)0.f; acc[j][1] = (f32x16)0.f; }

    // B staging source offsets (ushort units; + cgi*PXT*32 per chunk)
    int bgo[NBT];
    bool bgv[NBT];
    #pragma unroll
    for (int r = 0; r < NBT; r++) {
        int t = tid + 256 * r;
        bgv[r] = t < NBU;
        int tt = bgv[r] ? t : 0;
        int px = tt % NPX, kv = tt / NPX;
        int rr = px / SP, cc = px % SP;
        int Rc = R0 + rr; if (Rc > ROWMAX) Rc = ROWMAX;
        bgo[r] = (kv * PXT + Rc * SP + cc) * 8;
    }
    // A per-lane source: (( (cgi*9+r)*4 + nw)*512 + o0+lane)*8
    const int aoff = (nw * 512 + o0 + lane) * 8;

    auto stage = [&](int cgi, int buf) {
        ushort* dstA = &lds[buf * PAIR + nw * 512];
        ushort* dstB = &lds[buf * PAIR + ASZ + nw * 512];
        const ushort* asrc = wb + (size_t)cgi * 147456 + aoff;
        #pragma unroll
        for (int r = 0; r < 9; r++)
            gload_lds16(asrc + r * 16384, dstA + r * 2048);
        const ushort* bsrc = Xp + (size_t)cgi * (PXT * 32);
        #pragma unroll
        for (int r = 0; r < NBT; r++)
            if (bgv[r])
                gload_lds16(bsrc + bgo[r], dstB + r * 2048);
    };

    stage(ks * CK, 0);
    for (int c = 0; c < CK; c++) {
        const int cur = c & 1;
        if (c + 1 < CK) {
            stage(ks * CK + c + 1, cur ^ 1);
            asm volatile("s_waitcnt vmcnt(%0)" :: "i"(NMIN) : "memory");
        } else {
            asm volatile("s_waitcnt vmcnt(0)" ::: "memory");
        }
        __builtin_amdgcn_s_barrier();
        __builtin_amdgcn_sched_barrier(0);
        const int bo = cur * PAIR;
        #pragma unroll
        for (int t = 0; t < 9; t++) {
            const int dpx = (t / 3) * SP + (t % 3);
            #pragma unroll
            for (int s = 0; s < 2; s++) {
                const int kv = s * 2 + hf;
                bf16x8 a0 = *(const bf16x8*)&lds[bo + ((t * 4 + kv) * 64 + l31) * 8];
                bf16x8 a1 = *(const bf16x8*)&lds[bo + ((t * 4 + kv) * 64 + 32 + l31) * 8];
                #pragma unroll
                for (int j = 0; j < JCOLS; j++) {
                    bf16x8 bf = *(const bf16x8*)&lds[bo + ASZ + (kv * NPX + pixbase[j] + dpx) * 8];
                    acc[j][0] = __builtin_amdgcn_mfma_f32_32x32x16_bf16(a0, bf, acc[j][0], 0, 0, 0);
                    acc[j][1] = __builtin_amdgcn_mfma_f32_32x32x16_bf16(a1, bf, acc[j][1], 0, 0, 0);
                }
            }
        }
        __builtin_amdgcn_sched_barrier(0);
        __builtin_amdgcn_s_barrier();
    }

    if constexpr (KS > 1) {
        #pragma unroll
        for (int j = 0; j < JCOLS; j++) {
            float* pb = Pp + (((size_t)(ks * N + nj[j])) << 9) + o0;
            #pragma unroll
            for (int sub = 0; sub < 2; sub++) {
                #pragma unroll
                for (int rq = 0; rq < 4; rq++) {
                    float4 v = make_float4(acc[j][sub][rq * 4 + 0], acc[j][sub][rq * 4 + 1],
                                           acc[j][sub][rq * 4 + 2], acc[j][sub][rq * 4 + 3]);
                    *(float4*)&pb[sub * 32 + 4 * hf + 8 * rq] = v;
                }
            }
        }
        return;
    }
    float ns = nstr[0];
    #pragma unroll
    for (int j = 0; j < JCOLS; j++) {
        int n = nj[j], b = n / P2, r = n % P2;
        float nv = nz[b * P2 + r];
        int y = r / S, x = r % S;
        size_t tbase = (size_t)n << 9;
        int gpx = (b * SP + y + 1) * SP + x + 1;
        #pragma unroll
        for (int sub = 0; sub < 2; sub++) {
            #pragma unroll
            for (int rq = 0; rq < 4; rq++) {
                int o = o0 + sub * 32 + 4 * hf + 8 * rq;
                float4 d4 = *(const float4*)&dm[b * 512 + o];
                float4 b4 = *(const float4*)&bias[o];
                float vv[4];
                #pragma unroll
                for (int ri = 0; ri < 4; ri++) {
                    float v = acc[j][sub][rq * 4 + ri] * (&d4.x)[ri] * CONV_SCALE
                              + ns * nv + (&b4.x)[ri];
                    vv[ri] = (v > 0.f ? v : 0.2f * v) * SQRT2F;
                }
                store4bf(T + tbase + o, vv[0], vv[1], vv[2], vv[3]);
                if (WUP) {
                    float4 s4 = *(const float4*)&snext[b * 512 + o];
                    store4bf(XU + ((size_t)(o >> 3) * PXT + gpx) * 8 + (o & 7),
                             vv[0] * s4.x, vv[1] * s4.y, vv[2] * s4.z, vv[3] * s4.w);
                }
            }
        }
    }
}

// ============ K-split combine + epilogue (dense layers l0, l2, l4) ==========
// XU written g-major [g][px][8] for the following up-conv's B staging.
template <int S, int KS, bool WUP>
__global__ void combine_dense(const float* __restrict__ Pp, const float* __restrict__ dm,
                              const float* __restrict__ nz, const float* __restrict__ nstr,
                              const float* __restrict__ bias, const float* __restrict__ snext,
                              ushort* __restrict__ T, ushort* __restrict__ XU) {
    constexpr int P2 = S * S, N = 8 * P2, SP = S + 2;
    constexpr int PXT = 8 * SP * SP;
    int gid = blockIdx.x * 256 + threadIdx.x;
    int n = gid >> 7, og = (gid & 127) << 2;
    float4 sm = make_float4(0.f, 0.f, 0.f, 0.f);
    #pragma unroll
    for (int k = 0; k < KS; k++) {
        float4 p = *(const float4*)&Pp[(((size_t)(k * N + n)) << 9) + og];
        sm.x += p.x; sm.y += p.y; sm.z += p.z; sm.w += p.w;
    }
    int b = n / P2, r = n % P2;
    float nsv = nstr[0] * nz[b * P2 + r];
    float4 d4 = *(const float4*)&dm[b * 512 + og];
    float4 b4 = *(const float4*)&bias[og];
    float vv[4];
    const float* sp = &sm.x;
    #pragma unroll
    for (int i = 0; i < 4; i++) {
        float v = sp[i] * (&d4.x)[i] * CONV_SCALE + nsv + (&b4.x)[i];
        vv[i] = (v > 0.f ? v : 0.2f * v) * SQRT2F;
    }
    store4bf(&T[((size_t)n << 9) + og], vv[0], vv[1], vv[2], vv[3]);
    if (WUP) {
        int y = r / S, x = r % S;
        int gpx = (b * SP + y + 1) * SP + x + 1;
        float4 s4 = *(const float4*)&snext[b * 512 + og];
        store4bf(&XU[((size_t)(og >> 3) * PXT + gpx) * 8 + (og & 7)],
                 vv[0] * s4.x, vv[1] * s4.y, vv[2] * s4.z, vv[3] * s4.w);
    }
}

// ===== up-conv v5 (4 parity classes, coalesced DMA + dbuf + counted vmcnt) ==
// Xp g-major [g][px][8]; U output g-major for blur.
template <int HIN, int NTILE, int WRW>
__global__ __launch_bounds__(256, 2) void conv_up5(
    const ushort* __restrict__ Xp, const ushort* __restrict__ wb,
    const float* __restrict__ dm, ushort* __restrict__ U) {
    constexpr int SPI = HIN + 2, SOUT = 2 * HIN + 1, SPO = SOUT + 2;
    constexpr int PXT = 8 * SPI * SPI;
    constexpr int PXTO = 8 * SPO * SPO;
    constexpr int JCOLS = NTILE / 128;
    constexpr int NPX = WRW * SPI;
    constexpr int ASZ = 4 * 4 * 64 * 8;          // 8192 us per chunk
    constexpr int BSZ = NPX * 32;
    constexpr int PAIR = ASZ + BSZ;
    constexpr int NBU = NPX * 4;
    constexpr int NBT = (NBU + 255) / 256;
    constexpr int ROWMAX = 8 * SPI - 1;
    constexpr int MINB = (NBU > 192) ? ((NBU - 192 + 255) / 256) : 0;
    constexpr int NMIN = 4 + MINB;               // A staged as uniform 4 slots
    __shared__ __align__(16) ushort lds[2 * PAIR];

    const int py = blockIdx.z >> 1, pxp = blockIdx.z & 1;
    const int GY = py ? HIN : HIN + 1, GX = pxp ? HIN : HIN + 1;
    const int GG = GY * GX, NCLS = 8 * GG;
    const int NTY = py ? 1 : 2, NTX = pxp ? 1 : 2, NT = NTY * NTX;
    const int n0 = blockIdx.y * NTILE;
    if (n0 >= NCLS) return;

    int taplist[4], toffs[4];
    {
        int k = 0;
        #pragma unroll
        for (int a2 = 0; a2 < 2; a2++) {
            if (a2 >= NTY) break;
            int dy = py ? 1 : a2 * 2;
            #pragma unroll
            for (int c2 = 0; c2 < 2; c2++) {
                if (c2 >= NTX) break;
                int dx = pxp ? 1 : c2 * 2;
                taplist[k] = dy * 3 + dx;
                toffs[k] = ((dy + py) >> 1) * SPI + ((dx + pxp) >> 1);  // px units
                k++;
            }
        }
        for (; k < 4; k++) { taplist[k] = 0; toffs[k] = 0; }
    }

    const int tid = threadIdx.x, lane = tid & 63, nw = tid >> 6;
    const int hf = lane >> 5, l31 = lane & 31;
    const int o0 = blockIdx.x * 64;
    const int R0 = (n0 / GG) * SPI + (n0 % GG) / GX;

    int pixbase[JCOLS], bj[JCOLS], gyj[JCOLS], gxj[JCOLS];
    bool validj[JCOLS];
    #pragma unroll
    for (int j = 0; j < JCOLS; j++) {
        int n = n0 + nw * (NTILE / 4) + j * 32 + l31;
        validj[j] = n < NCLS;
        int nc = validj[j] ? n : (NCLS - 1);
        int b = nc / GG, rem = nc % GG;
        int gy = rem / GX, gx = rem % GX;
        bj[j] = b; gyj[j] = gy; gxj[j] = gx;
        pixbase[j] = (b * SPI + gy - R0) * SPI + gx;  // px units
    }
    f32x16 acc[JCOLS][2];
    #pragma unroll
    for (int j = 0; j < JCOLS; j++) { acc[j][0] = (f32x16)0.f; acc[j][1] = (f32x16)0.f; }

    int bgo[NBT];
    bool bgv[NBT];
    #pragma unroll
    for (int r = 0; r < NBT; r++) {
        int t = tid + 256 * r;
        bgv[r] = t < NBU;
        int tt = bgv[r] ? t : 0;
        int px = tt % NPX, kv = tt / NPX;
        int rr = px / SPI, cc = px % SPI;
        int Rc = R0 + rr; if (Rc > ROWMAX) Rc = ROWMAX;
        bgo[r] = (kv * PXT + Rc * SPI + cc) * 8;
    }
    const int aoff = (nw * 512 + o0 + lane) * 8;
    int atap[4];
    #pragma unroll
    for (int r = 0; r < 4; r++) atap[r] = taplist[r] * 16384;

    auto stage = [&](int cgi, int buf) {
        ushort* dstA = &lds[buf * PAIR + nw * 512];
        ushort* dstB = &lds[buf * PAIR + ASZ + nw * 512];
        const ushort* asrc = wb + (size_t)cgi * 147456 + aoff;
        #pragma unroll
        for (int r = 0; r < 4; r++)   // uniform 4 A-slots (pad taps repeat tap0)
            gload_lds16(asrc + atap[r], dstA + r * 2048);
        const ushort* bsrc = Xp + (size_t)cgi * (PXT * 32);
        #pragma unroll
        for (int r = 0; r < NBT; r++)
            if (bgv[r])
                gload_lds16(bsrc + bgo[r], dstB + r * 2048);
    };

    stage(0, 0);
    for (int c = 0; c < 16; c++) {
        const int cur = c & 1;
        if (c + 1 < 16) {
            stage(c + 1, cur ^ 1);
            asm volatile("s_waitcnt vmcnt(%0)" :: "i"(NMIN) : "memory");
        } else {
            asm volatile("s_waitcnt vmcnt(0)" ::: "memory");
        }
        __builtin_amdgcn_s_barrier();
        __builtin_amdgcn_sched_barrier(0);
        const int bo = cur * PAIR;
        for (int tt = 0; tt < NT; ++tt) {
            const int dpx = toffs[tt];
            #pragma unroll
            for (int s = 0; s < 2; s++) {
                const int kv = s * 2 + hf;
                bf16x8 a0 = *(const bf16x8*)&lds[bo + ((tt * 4 + kv) * 64 + l31) * 8];
                bf16x8 a1 = *(const bf16x8*)&lds[bo + ((tt * 4 + kv) * 64 + 32 + l31) * 8];
                #pragma unroll
                for (int j = 0; j < JCOLS; j++) {
                    bf16x8 bf = *(const bf16x8*)&lds[bo + ASZ + (kv * NPX + pixbase[j] + dpx) * 8];
                    acc[j][0] = __builtin_amdgcn_mfma_f32_32x32x16_bf16(a0, bf, acc[j][0], 0, 0, 0);
                    acc[j][1] = __builtin_amdgcn_mfma_f32_32x32x16_bf16(a1, bf, acc[j][1], 0, 0, 0);
                }
            }
        }
        __builtin_amdgcn_sched_barrier(0);
        __builtin_amdgcn_s_barrier();
    }
    #pragma unroll
    for (int j = 0; j < JCOLS; j++) {
        if (!validj[j]) continue;
        int b = bj[j];
        int y = 2 * gyj[j] + py, x = 2 * gxj[j] + pxp;
        int gpx = (b * SPO + y + 1) * SPO + x + 1;
        #pragma unroll
        for (int sub = 0; sub < 2; sub++) {
            #pragma unroll
            for (int rq = 0; rq < 4; rq++) {
                int o = o0 + sub * 32 + 4 * hf + 8 * rq;
                float4 d4 = *(const float4*)&dm[b * 512 + o];
                float vv[4];
                #pragma unroll
                for (int ri = 0; ri < 4; ri++)
                    vv[ri] = acc[j][sub][rq * 4 + ri] * (&d4.x)[ri] * CONV_SCALE;
                store4bf(U + ((size_t)(o >> 3) * PXTO + gpx) * 8 + (o & 7),
                         vv[0], vv[1], vv[2], vv[3]);
            }
        }
    }
}

// ========= blur 4x4 + noise + bias + lrelu + style (g-major in/out) =========
template <int SIN>
__global__ void blur_px(const ushort* __restrict__ U, const float* __restrict__ nz,
                        const float* __restrict__ nstr, const float* __restrict__ bias,
                        const float* __restrict__ snext, ushort* __restrict__ X) {
    constexpr int O = SIN - 1, SPI = SIN + 2, SPO = O + 2;
    constexpr int PXTU = 8 * SPI * SPI;
    constexpr int PXTO = 8 * SPO * SPO;
    int gid = blockIdx.x * 256 + threadIdx.x;
    if (gid >= 8 * O * O * 64) return;
    int grp = gid & 63;
    int pxl = gid >> 6;
    int b = pxl / (O * O), r = pxl % (O * O), u = r / O, vcol = r % O;
    const float k1[4] = {0.25f, 0.75f, 0.75f, 0.25f};
    float acc[8];
    #pragma unroll
    for (int k = 0; k < 8; k++) acc[k] = 0.f;
    const ushort* Ug = U + (size_t)grp * PXTU * 8;
    #pragma unroll
    for (int a = 0; a < 4; a++) {
        int row = b * SPI + u + a;
        #pragma unroll
        for (int c = 0; c < 4; c++) {
            float w = k1[a] * k1[c];
            bf16x8 v = *(const bf16x8*)&Ug[(size_t)(row * SPI + vcol + c) * 8];
            #pragma unroll
            for (int k = 0; k < 8; k++) acc[k] += w * bf2f((ushort)v[k]);
        }
    }
    float nsv = nstr[0] * nz[b * O * O + r];
    float4 b0 = *(const float4*)&bias[grp * 8];
    float4 b1 = *(const float4*)&bias[grp * 8 + 4];
    float4 s0 = *(const float4*)&snext[b * 512 + grp * 8];
    float4 s1 = *(const float4*)&snext[b * 512 + grp * 8 + 4];
    union { ushort us[8]; bf16x8 v; } pk;
    #pragma unroll
    for (int k = 0; k < 8; k++) {
        float bk = (k < 4) ? (&b0.x)[k] : (&b1.x)[k - 4];
        float sk = (k < 4) ? (&s0.x)[k] : (&s1.x)[k - 4];
        float v = acc[k] + nsv + bk;
        v = (v > 0.f ? v : 0.2f * v) * SQRT2F;
        pk.us[k] = f2bf(v * sk);
    }
    *(bf16x8*)&X[((size_t)grp * PXTO + (b * SPO + u + 1) * SPO + vcol + 1) * 8] = pk.v;
}

// ======================== skip upsample (up=2, pad 2,1) =====================
template <int H>
__global__ void skipup_kernel(const float* __restrict__ skip, float* __restrict__ out) {
    constexpr int O = 2 * H;
    int idx = blockIdx.x * 256 + threadIdx.x;
    if (idx >= 8 * 3 * O * O) return;
    int px = idx % (O * O);
    int bc = idx / (O * O);
    int u = px / O, v = px % O;
    const float k1[4] = {0.25f, 0.75f, 0.75f, 0.25f};
    const float* src = skip + (size_t)bc * (H * H);
    float acc = 0.f;
    #pragma unroll
    for (int ty = 0; ty < 4; ty++) {
        int r = u + ty - 2;
        if (r < 0 || (r & 1) || (r >> 1) >= H) continue;
        float rsum = 0.f;
        #pragma unroll
        for (int tx = 0; tx < 4; tx++) {
            int cc = v + tx - 2;
            if (cc < 0 || (cc & 1) || (cc >> 1) >= H) continue;
            rsum += k1[tx] * src[(r >> 1) * H + (cc >> 1)];
        }
        acc += k1[ty] * rsum;
    }
    out[(size_t)bc * (O * O) + px] = acc;
}

// ============================ to_rgb (px-major T) ===========================
__global__ void torgb_px(const ushort* __restrict__ T, int P2,
                         const float* __restrict__ rgbw, const float* __restrict__ srgb,
                         const float* __restrict__ rbias, const float* __restrict__ skipup,
                         float* __restrict__ dst) {
    int b = blockIdx.x;
    int px = blockIdx.y * 4 + (threadIdx.x >> 6);
    int lane = threadIdx.x & 63;
    int c8 = lane * 8;
    bf16x8 v = *(const bf16x8*)&T[(((size_t)b * P2 + px) << 9) + c8];
    float4 sa = *(const float4*)&srgb[b * 512 + c8];
    float4 sb = *(const float4*)&srgb[b * 512 + c8 + 4];
    float xs[8];
    #pragma unroll
    for (int k = 0; k < 8; k++) {
        float sk = (k < 4) ? (&sa.x)[k] : (&sb.x)[k - 4];
        xs[k] = bf2f((ushort)v[k]) * sk;
    }
    float sums[3];
    #pragma unroll
    for (int c = 0; c < 3; c++) {
        float4 w0 = *(const float4*)&rgbw[c * 512 + c8];
        float4 w1 = *(const float4*)&rgbw[c * 512 + c8 + 4];
        float s = 0.f;
        #pragma unroll
        for (int k = 0; k < 8; k++) {
            float wk = (k < 4) ? (&w0.x)[k] : (&w1.x)[k - 4];
            s += xs[k] * wk;
        }
        #pragma unroll
        for (int off = 32; off > 0; off >>= 1) s += __shfl_xor(s, off, 64);
        sums[c] = s;
    }
    if (lane == 0) {
        #pragma unroll
        for (int c = 0; c < 3; c++) {
            float o = sums[c] * RGB_SCALE + rbias[c];
            if (skipup) o += skipup[((size_t)b * 3 + c) * P2 + px];
            dst[((size_t)b * 3 + c) * P2 + px] = o;
        }
    }
}

// ================================ launch ====================================

extern "C" void kernel_launch(void* const* d_in, const int* in_sizes, int n_in,
                              void* d_out, int out_size, void* d_ws, size_t ws_size,
                              hipStream_t stream) {
    const float* z      = (const float*)d_in[0];
    const float* mlp_w  = (const float*)d_in[1];
    const float* mlp_b  = (const float*)d_in[2];
    const float* cinp   = (const float*)d_in[3];
    const float* conv_w = (const float*)d_in[4];
    const float* cmw    = (const float*)d_in[5];
    const float* cmb    = (const float*)d_in[6];
    const float* cbias  = (const float*)d_in[7];
    const float* nstr   = (const float*)d_in[8];
    const float* rgbw   = (const float*)d_in[9];
    const float* rmw    = (const float*)d_in[10];
    const float* rmb    = (const float*)d_in[11];
    const float* rbias  = (const float*)d_in[12];
    float* out = (float*)d_out;
    float* ws = (float*)d_ws;

    // ---- workspace (float-slot offsets) ----
    float* wlatA = ws;                        // 4096
    float* wlatB = ws + 4096;                 // 4096
    float* sconv = ws + 8192;                 // 7*4096
    float* srgb  = ws + 36864;                // 4*4096
    float* dem   = ws + 53248;                // 7*4096
    float* noise = ws + 81920;                // 21632
    float* skipA = ws + 103552;               // 24576
    float* skipB = ws + 128128;               // 24576
    float* skipU = ws + 152704;               // 24576 -> 177280
    float* wsq7  = ws + 177280;               // 7*262144 = 1835008 -> 2012288
    ushort* wbuf7 = (ushort*)(ws + 2012288);  // 7*2359296 us = 8257536 f -> 10269824
    float* Ppart = ws + 10269824;             // 2097152 -> 12366976
    ushort* A1 = (ushort*)(ws + 12366976);    // 5017600 us -> f 14875776
    ushort* A2 = (ushort*)(ws + 14875776);    // 4734976 us -> f 17243264
    ushort* A3 = (ushort*)(ws + 17243264);    // 4194304 us -> f 19340416

    // arena aliases (lifetimes disjoint)
    ushort* X0p = A1;   // g-major 64*288*8
    ushort* T0  = A2;   // px-major 8*16*512
    ushort* XU1 = A3;   // g-major 64*288*8
    ushort* U1  = A1;   // g-major 64*968*8
    ushort* X2  = A2;   // g-major 64*800*8
    ushort* T2  = A3;   // px-major 8*64*512
    ushort* XU3 = A1;   // g-major 64*800*8
    ushort* U3  = A2;   // g-major 64*2888*8
    ushort* X4  = A1;   // g-major 64*2592*8
    ushort* T4  = A2;   // px-major 8*256*512
    ushort* XU5 = A3;   // g-major 64*2592*8
    ushort* U5  = A1;   // g-major 64*9800*8
    ushort* X6  = A2;   // g-major 64*9248*8
    ushort* T6  = A3;   // px-major 8*1024*512

    const size_t LWB = 2359296;  // us per layer in wbuf7

    // weights repack (all layers) + noise (independent of mapping)
    wbconv_all<<<896, 256, 0, stream>>>(conv_w, wbuf7, wsq7);
    noise_kernel<<<85, 256, 0, stream>>>(noise);

    // mapping network
    pixelnorm_kernel<<<8, 64, 0, stream>>>(z, wlatA);
    float* a = wlatA;
    float* bb = wlatB;
    for (int i = 0; i < 8; i++) {
        dot512_kernel<<<1024, 256, 0, stream>>>(a, mlp_w + (size_t)i * 262144,
                                                mlp_b + i * 512, bb, 4096,
                                                MAP_SCALE, 0.01f, 1);
        float* t = a; a = bb; bb = t;
    }
    dot512_kernel<<<7168, 256, 0, stream>>>(a, cmw, cmb, sconv, 7 * 4096, MOD_SCALE, 1.0f, 0);
    dot512_kernel<<<4096, 256, 0, stream>>>(a, rmw, rmb, srgb, 4 * 4096, MOD_SCALE, 1.0f, 0);
    demod_all<<<7168, 256, 0, stream>>>(wsq7, sconv, dem);
    prep0_kernel<<<72, 256, 0, stream>>>(cinp, sconv, X0p);

    // ---- layer 0 (dense 4x4, K-split 16 -> 128 blocks, single-chunk) ----
    conv_dense5<4, 128, 48, 16, false><<<dim3(8, 1, 16), 256, 0, stream>>>(
        X0p, wbuf7, nullptr, nullptr, nullptr, nullptr, nullptr,
        nullptr, nullptr, Ppart);
    hipMemsetAsync(XU1, 0, (size_t)8 * 36 * 512 * 2, stream);
    combine_dense<4, 16, true><<<64, 256, 0, stream>>>(
        Ppart, dem, noise, nstr, cbias, sconv + 4096, T0, XU1);
    torgb_px<<<dim3(8, 4), 256, 0, stream>>>(T0, 16, rgbw, srgb, rbias, nullptr, skipA);

    // ---- layer 1 (up 4->9, all classes) ----
    hipMemsetAsync(U1, 0, (size_t)8 * 121 * 512 * 2, stream);
    conv_up5<4, 128, 48><<<dim3(8, 2, 4), 256, 0, stream>>>(XU1, wbuf7 + LWB, dem + 4096, U1);
    hipMemsetAsync(X2, 0, (size_t)8 * 100 * 512 * 2, stream);
    blur_px<9><<<128, 256, 0, stream>>>(U1, noise + 128, nstr + 1, cbias + 512,
                                        sconv + 2 * 4096, X2);

    // ---- layer 2 (dense 8x8, K-split 8 -> 256 blocks) ----
    conv_dense5<8, 128, 20, 8, false><<<dim3(8, 4, 8), 256, 0, stream>>>(
        X2, wbuf7 + 2 * LWB, nullptr, nullptr, nullptr, nullptr, nullptr,
        nullptr, nullptr, Ppart);
    hipMemsetAsync(XU3, 0, (size_t)8 * 100 * 512 * 2, stream);
    combine_dense<8, 8, true><<<256, 256, 0, stream>>>(
        Ppart, dem + 2 * 4096, noise + 640, nstr + 2, cbias + 2 * 512,
        sconv + 3 * 4096, T2, XU3);
    skipup_kernel<4><<<6, 256, 0, stream>>>(skipA, skipU);
    torgb_px<<<dim3(8, 16), 256, 0, stream>>>(T2, 64, rgbw + 1536, srgb + 4096,
                                              rbias + 3, skipU, skipB);

    // ---- layer 3 (up 8->17, all classes) ----
    hipMemsetAsync(U3, 0, (size_t)8 * 361 * 512 * 2, stream);
    conv_up5<8, 128, 22><<<dim3(8, 6, 4), 256, 0, stream>>>(XU3, wbuf7 + 3 * LWB,
                                                            dem + 3 * 4096, U3);
    hipMemsetAsync(X4, 0, (size_t)8 * 324 * 512 * 2, stream);
    blur_px<17><<<512, 256, 0, stream>>>(U3, noise + 1152, nstr + 3, cbias + 3 * 512,
                                         sconv + 4 * 4096, X4);

    // ---- layer 4 (dense 16x16, NTILE=128, K-split 2 -> 256 blocks) ----
    conv_dense5<16, 128, 10, 2, false><<<dim3(8, 16, 2), 256, 0, stream>>>(
        X4, wbuf7 + 4 * LWB, nullptr, nullptr, nullptr, nullptr, nullptr,
        nullptr, nullptr, Ppart);
    hipMemsetAsync(XU5, 0, (size_t)8 * 324 * 512 * 2, stream);
    combine_dense<16, 2, true><<<1024, 256, 0, stream>>>(
        Ppart, dem + 4 * 4096, noise + 3200, nstr + 4, cbias + 4 * 512,
        sconv + 5 * 4096, T4, XU5);
    skipup_kernel<8><<<24, 256, 0, stream>>>(skipB, skipU);
    torgb_px<<<dim3(8, 64), 256, 0, stream>>>(T4, 256, rgbw + 2 * 1536, srgb + 2 * 4096,
                                              rbias + 6, skipU, skipA);

    // ---- layer 5 (up 16->33, all classes) ----
    hipMemsetAsync(U5, 0, (size_t)8 * 1225 * 512 * 2, stream);
    conv_up5<16, 256, 20><<<dim3(8, 10, 4), 256, 0, stream>>>(XU5, wbuf7 + 5 * LWB,
                                                              dem + 5 * 4096, U5);
    hipMemsetAsync(X6, 0, (size_t)8 * 1156 * 512 * 2, stream);
    blur_px<33><<<2048, 256, 0, stream>>>(U5, noise + 5248, nstr + 5, cbias + 5 * 512,
                                          sconv + 6 * 4096, X6);

    // ---- layer 6 (dense 32x32, NTILE=256 -> 256 blocks = 1/CU, pipelined) ----
    conv_dense5<32, 256, 10, 1, false><<<dim3(8, 32, 1), 256, 0, stream>>>(
        X6, wbuf7 + 6 * LWB, dem + 6 * 4096, noise + 13440, nstr + 6, cbias + 6 * 512,
        nullptr, T6, nullptr, nullptr);
    skipup_kernel<16><<<96, 256, 0, stream>>>(skipA, skipU);
    torgb_px<<<dim3(8, 256), 256, 0, stream>>>(T6, 1024, rgbw + 3 * 1536, srgb + 3 * 4096,
                                               rbias + 9, skipU, out);
}

// Round 8
// 403.965 us; speedup vs baseline: 1.0645x; 1.0645x over previous
//
#include <hip/hip_runtime.h>

// ---------------------------------------------------------------------------
// StyleGAN2-like generator forward. Convs via bf16 MFMA implicit GEMM,
// A+B staged via global_load_lds DMA with coalesced sources.
// R8: dense convs -> 512-thread blocks with K-split across wave-halves.
//   R7 post-mortem: l6 at MfmaUtil 32%, 1 wave/SIMD (117KB LDS -> 1 blk/CU);
//   per-chunk MFMA cycles == LDS ds_read cycles (2304 each) but SERIALIZED
//   (no co-resident wave to overlap). Fix: 8 waves/block; waves 0-3 take
//   kv{0,1}, waves 4-7 take kv{2,3} of the same chunk (read:MFMA ratio
//   unchanged), LDS reduction merges K-halves at the end -> 2 waves/SIMD.
//   Also wbconv_all rewritten with LDS transpose (coalesced reads AND
//   writes; R7's thread remap left reads at 64-lines/instr).
// B=8, C=512, output [8,3,32,32] f32.
// ---------------------------------------------------------------------------

#define SQRT2F      1.41421356f
#define MAP_SCALE   4.41941738e-04f   // 0.01/sqrt(512)
#define MOD_SCALE   4.41941738e-02f   // 1/sqrt(512)
#define CONV_SCALE  1.47313913e-02f   // 1/sqrt(512*9)
#define RGB_SCALE   4.41941738e-02f   // 1/sqrt(512)

typedef __attribute__((ext_vector_type(8))) short bf16x8;
typedef __attribute__((ext_vector_type(16))) float f32x16;

__device__ __forceinline__ float bf2f(ushort u) {
    return __uint_as_float(((unsigned)u) << 16);
}
__device__ __forceinline__ ushort f2bf(float f) {
    unsigned u = __float_as_uint(f);
    unsigned r = (u + 0x7FFFu + ((u >> 16) & 1u)) >> 16;
    return (ushort)r;
}
__device__ __forceinline__ void store4bf(ushort* p, float a, float b, float c, float d) {
    union { ushort u[4]; uint2 v; } x;
    x.u[0] = f2bf(a); x.u[1] = f2bf(b); x.u[2] = f2bf(c); x.u[3] = f2bf(d);
    *(uint2*)p = x.v;
}

// direct global->LDS DMA, 16B per lane. LDS dest wave-uniform base + lane*16;
// global source is per-lane.
typedef __attribute__((address_space(1))) const unsigned int GAS;
typedef __attribute__((address_space(3))) unsigned int LAS;
__device__ __forceinline__ void gload_lds16(const ushort* g, ushort* l) {
    __builtin_amdgcn_global_load_lds((GAS*)g, (LAS*)l, 16, 0, 0);
}

// ============================ PRNG (JAX threefry) ===========================

__device__ __forceinline__ unsigned rotl32(unsigned x, int r) {
    return (x << r) | (x >> (32 - r));
}

__device__ void threefry2x32(unsigned k0, unsigned k1, unsigned x0, unsigned x1,
                             unsigned& o0, unsigned& o1) {
    unsigned k2 = k0 ^ k1 ^ 0x1BD11BDAu;
    x0 += k0; x1 += k1;
    x0 += x1; x1 = rotl32(x1,13); x1 ^= x0;
    x0 += x1; x1 = rotl32(x1,15); x1 ^= x0;
    x0 += x1; x1 = rotl32(x1,26); x1 ^= x0;
    x0 += x1; x1 = rotl32(x1, 6); x1 ^= x0;
    x0 += k1; x1 += k2 + 1u;
    x0 += x1; x1 = rotl32(x1,17); x1 ^= x0;
    x0 += x1; x1 = rotl32(x1,29); x1 ^= x0;
    x0 += x1; x1 = rotl32(x1,16); x1 ^= x0;
    x0 += x1; x1 = rotl32(x1,24); x1 ^= x0;
    x0 += k2; x1 += k0 + 2u;
    x0 += x1; x1 = rotl32(x1,13); x1 ^= x0;
    x0 += x1; x1 = rotl32(x1,15); x1 ^= x0;
    x0 += x1; x1 = rotl32(x1,26); x1 ^= x0;
    x0 += x1; x1 = rotl32(x1, 6); x1 ^= x0;
    x0 += k0; x1 += k1 + 3u;
    x0 += x1; x1 = rotl32(x1,17); x1 ^= x0;
    x0 += x1; x1 = rotl32(x1,29); x1 ^= x0;
    x0 += x1; x1 = rotl32(x1,16); x1 ^= x0;
    x0 += x1; x1 = rotl32(x1,24); x1 ^= x0;
    x0 += k1; x1 += k2 + 4u;
    x0 += x1; x1 = rotl32(x1,13); x1 ^= x0;
    x0 += x1; x1 = rotl32(x1,15); x1 ^= x0;
    x0 += x1; x1 = rotl32(x1,26); x1 ^= x0;
    x0 += x1; x1 = rotl32(x1, 6); x1 ^= x0;
    x0 += k2; x1 += k0 + 5u;
    o0 = x0; o1 = x1;
}

__device__ float bits_to_normal(unsigned bits) {
    unsigned m = (bits >> 9) | 0x3F800000u;
    float f = __uint_as_float(m) - 1.0f;
    const float lo = -0.99999994f;
    float u = f * 2.0f + lo;
    u = fmaxf(lo, u);
    float w = -log1pf(-u * u);
    float p;
    if (w < 5.0f) {
        w -= 2.5f;
        p = 2.81022636e-08f;
        p = fmaf(p, w, 3.43273939e-07f);
        p = fmaf(p, w, -3.5233877e-06f);
        p = fmaf(p, w, -4.39150654e-06f);
        p = fmaf(p, w, 0.00021858087f);
        p = fmaf(p, w, -0.00125372503f);
        p = fmaf(p, w, -0.00417768164f);
        p = fmaf(p, w, 0.246640727f);
        p = fmaf(p, w, 1.50140941f);
    } else {
        w = sqrtf(w) - 3.0f;
        p = -0.000200214257f;
        p = fmaf(p, w, 0.000100950558f);
        p = fmaf(p, w, 0.00134934322f);
        p = fmaf(p, w, -0.00367342844f);
        p = fmaf(p, w, 0.00573950773f);
        p = fmaf(p, w, -0.0076224613f);
        p = fmaf(p, w, 0.00943887047f);
        p = fmaf(p, w, 1.00167406f);
        p = fmaf(p, w, 2.83297682f);
    }
    return 1.41421354f * (p * u);
}

__global__ void noise_kernel(float* __restrict__ nbuf) {
    int g = blockIdx.x * 256 + threadIdx.x;
    if (g >= 21632) return;
    const int off[8] = {0, 128, 640, 1152, 3200, 5248, 13440, 21632};
    int l = 0;
    while (l < 6 && g >= off[l + 1]) l++;
    int i = g - off[l];
    unsigned k0, k1;
    threefry2x32(0u, 7u, 0u, (unsigned)l, k0, k1);
    unsigned b0, b1;
    threefry2x32(k0, k1, 0u, (unsigned)i, b0, b1);
    nbuf[g] = bits_to_normal(b0 ^ b1);
}

// ============================ small linear kernels ==========================

__global__ void pixelnorm_kernel(const float* __restrict__ z, float* __restrict__ out) {
    int b = blockIdx.x;
    int lane = threadIdx.x;
    float v[8];
    float s = 0.f;
    #pragma unroll
    for (int j = 0; j < 8; j++) {
        v[j] = z[b * 512 + lane + (j << 6)];
        s += v[j] * v[j];
    }
    #pragma unroll
    for (int off = 32; off > 0; off >>= 1) s += __shfl_xor(s, off, 64);
    float norm = rsqrtf(s * (1.f / 512.f) + 1e-8f);
    #pragma unroll
    for (int j = 0; j < 8; j++)
        out[b * 512 + lane + (j << 6)] = v[j] * norm;
}

__global__ void dot512_kernel(const float* __restrict__ win, const float* __restrict__ W,
                              const float* __restrict__ bias, float* __restrict__ out,
                              int total, float wscale, float bscale, int mode) {
    int gt = blockIdx.x * blockDim.x + threadIdx.x;
    int wv = gt >> 6;
    int lane = gt & 63;
    if (wv >= total) return;
    int l = wv >> 12;
    int r = wv & 4095;
    int b = r >> 9;
    int o = r & 511;
    const float* wrow = W + ((size_t)(l * 512 + o) << 9);
    const float* xrow = win + ((size_t)b << 9);
    float s = 0.f;
    #pragma unroll
    for (int j = 0; j < 8; j++) {
        int k = lane + (j << 6);
        s += wrow[k] * xrow[k];
    }
    #pragma unroll
    for (int off = 32; off > 0; off >>= 1) s += __shfl_xor(s, off, 64);
    if (lane == 0) {
        float v = s * wscale + bias[l * 512 + o] * bscale;
        if (mode) v = (v > 0.f ? v : 0.2f * v) * SQRT2F;
        out[wv] = v;
    }
}

// weight repack to coalesced-DMA layout: wb[l][c][t][kv][o][8e]
// (i = c*32+kv*8+e). flip taps for l=1,3,5. + wsq7[l][o][i].
// R8: LDS-transpose version. Block = (l, c, og): reads cw[l][o0..o0+63]
// [c*32..+31][*] as coalesced float4 runs, stages into lg[row=i*9+t][o]
// (stride 65 to kill bank conflicts on the strided phases), then emits
// coalesced 1KB uint4 write segments + wsq.
__global__ __launch_bounds__(256) void wbconv_all(const float* __restrict__ cw,
                                                  ushort* __restrict__ wb7,
                                                  float* __restrict__ wsq7) {
    __shared__ float lg[288 * 65];               // 74880 B
    const int bid = blockIdx.x;
    const int l = bid >> 7, rem = bid & 127, c = rem >> 3, og = rem & 7;
    const int o0 = og * 64;
    const int ibase = c * 32;
    const int tid = threadIdx.x;
    const int flip = (l == 1 || l == 3 || l == 5);

    // phase 1: 4608 16B-units; u = o*72 + w (w = 16B unit within the 288-float
    // (i,t) row). Reads contiguous within each o-run; LDS scatter transpose.
    #pragma unroll
    for (int r = 0; r < 18; r++) {
        int u = tid + 256 * r;
        int o = u / 72, w = u % 72;
        const float* src = cw + ((size_t)((l * 512 + o0 + o) * 512 + ibase)) * 9 + w * 4;
        float4 v = *(const float4*)src;
        lg[(w * 4 + 0) * 65 + o] = v.x;
        lg[(w * 4 + 1) * 65 + o] = v.y;
        lg[(w * 4 + 2) * 65 + o] = v.z;
        lg[(w * 4 + 3) * 65 + o] = v.w;
    }
    __syncthreads();

    // phase 2a: wsq. u = o*32 + il; lanes step il -> bank stride 9*65 (coprime
    // with 32) = conflict-free; writes 128B contiguous per o.
    #pragma unroll
    for (int r = 0; r < 8; r++) {
        int u = tid + 256 * r;                   // < 2048
        int o = u >> 5, il = u & 31;
        float s = 0.f;
        #pragma unroll
        for (int t = 0; t < 9; t++) {
            float x = lg[(il * 9 + t) * 65 + o];
            s += x * x;
        }
        wsq7[((size_t)(l * 512 + o0 + o)) * 512 + ibase + il] = s;
    }

    // phase 2b: pack+write. u = (t*4+kv)*64 + o; lanes step o -> LDS reads
    // conflict-free, global writes = contiguous 1KB segments.
    ushort* wb = wb7 + (size_t)l * 2359296;
    #pragma unroll
    for (int r = 0; r < 9; r++) {
        int u = tid + 256 * r;                   // < 2304
        int o = u & 63, tk = u >> 6;
        int t = tk >> 2, kv = tk & 3;
        int tsrc = flip ? (8 - t) : t;
        union { ushort us[8]; uint4 v; } pk;
        #pragma unroll
        for (int e = 0; e < 8; e++)
            pk.us[e] = f2bf(lg[((kv * 8 + e) * 9 + tsrc) * 65 + o]);
        *(uint4*)&wb[(size_t)(((c * 9 + t) * 4 + kv) * 512 + o0 + o) * 8] = pk.v;
    }
}

// all-layer demod: dm[l][b][o]
__global__ void demod_all(const float* __restrict__ wsq7, const float* __restrict__ sc,
                          float* __restrict__ dm) {
    int gt = blockIdx.x * blockDim.x + threadIdx.x;
    int wv = gt >> 6;
    int lane = gt & 63;
    if (wv >= 7 * 4096) return;
    int l = wv >> 12, b = (wv >> 9) & 7, o = wv & 511;
    const float* wr = wsq7 + (size_t)l * 262144 + ((size_t)o << 9);
    const float* sr = sc + l * 4096 + (b << 9);
    float s = 0.f;
    #pragma unroll
    for (int j = 0; j < 8; j++) {
        int k = lane + (j << 6);
        float sv = sr[k];
        s += wr[k] * sv * sv;
    }
    #pragma unroll
    for (int off = 32; off > 0; off >>= 1) s += __shfl_xor(s, off, 64);
    if (lane == 0) dm[wv] = rsqrtf(s * (1.f / 4608.f) + 1e-8f);
}

// prep l0 input, g-major: X0p[g=ch/8][px(288)][8] = styled padded const_input
__global__ void prep0_kernel(const float* __restrict__ cinp, const float* __restrict__ s0,
                             ushort* __restrict__ X0p) {
    int gid = blockIdx.x * 256 + threadIdx.x;
    if (gid >= 8 * 36 * 64) return;
    int grp = gid & 63;
    int r = gid >> 6;             // px index 0..287 (b*36 + row*6 + col)
    int b = r / 36, rc = r % 36, row = rc / 6, col = rc % 6;
    int y = row - 1, x = col - 1;
    union { ushort u[8]; bf16x8 v; } pk;
    if (y >= 0 && y < 4 && x >= 0 && x < 4) {
        #pragma unroll
        for (int k = 0; k < 8; k++) {
            int ch = grp * 8 + k;
            pk.u[k] = f2bf(cinp[ch * 16 + y * 4 + x] * s0[b * 512 + ch]);
        }
    } else {
        #pragma unroll
        for (int k = 0; k < 8; k++) pk.u[k] = 0;
    }
    *(bf16x8*)&X0p[((size_t)grp * 288 + r) * 8] = pk.v;
}

// === dense conv v6: 8-wave K-split + coalesced DMA + dbuf + counted vmcnt ===
// 512 threads. Waves 0-3 (sw=0) compute kv{0,1}, waves 4-7 (sw=1) kv{2,3};
// wave-quarter nww owns the same n-range in both halves. LDS reduction merges
// the K-halves before the epilogue (waves 0-3 finish).
template <int S, int NTILE, int WROWS, int KS, bool WUP>
__global__ __launch_bounds__(512, 1) void conv_dense6(
    const ushort* __restrict__ Xp, const ushort* __restrict__ wb,
    const float* __restrict__ dm, const float* __restrict__ nz,
    const float* __restrict__ nstr, const float* __restrict__ bias,
    const float* __restrict__ snext,
    ushort* __restrict__ T, ushort* __restrict__ XU, float* __restrict__ Pp) {
    constexpr int SP = S + 2, P2 = S * S, N = 8 * P2;
    constexpr int PXT = 8 * SP * SP;             // total padded px
    constexpr int JCOLS = NTILE / 128;
    constexpr int NPX = WROWS * SP;
    constexpr int ASZ = 9 * 4 * 64 * 8;          // 18432 us per chunk
    constexpr int BSZ = NPX * 32;                // us per chunk
    constexpr int PAIR = ASZ + BSZ;
    constexpr int NAU = 2304;                    // A 16B units per chunk
    constexpr int NAT = 5;                       // ceil(2304/512)
    constexpr int NBU = NPX * 4;                 // B 16B units per chunk
    constexpr int NBT = (NBU + 511) / 512;
    constexpr int ROWMAX = 8 * SP - 1;
    constexpr int CK = 16 / KS;
    constexpr int DB = (CK > 1) ? 2 : 1;
    constexpr int NAF = 4;                       // full A rounds (min per wave)
    constexpr int NBF = NBU / 512;               // full B rounds
    constexpr int NMIN = NAF + NBF;
    constexpr int REDU = JCOLS * 16384;          // reduction buffer (us)
    constexpr int LDSZ = (DB * PAIR > REDU) ? DB * PAIR : REDU;
    __shared__ __align__(16) ushort lds[LDSZ];

    const int tid = threadIdx.x, lane = tid & 63, nw = tid >> 6;
    const int sw = nw >> 2, nww = nw & 3;
    const int hf = lane >> 5, l31 = lane & 31;
    const int o0 = blockIdx.x * 64;
    const int n0 = blockIdx.y * NTILE;
    const int ks = blockIdx.z;
    const int R0 = (n0 / P2) * SP + (n0 % P2) / S;
    const int kvw = sw * 2 + hf;                 // this wave's kv slice

    int pixbase[JCOLS], nj[JCOLS];
    #pragma unroll
    for (int j = 0; j < JCOLS; j++) {
        int n = n0 + nww * (NTILE / 4) + j * 32 + l31;
        nj[j] = n;
        int b = n / P2, r = n % P2;
        int y = r / S, x = r % S;
        pixbase[j] = (b * SP + y - R0) * SP + x;   // px units
    }
    f32x16 acc[JCOLS][2];
    #pragma unroll
    for (int j = 0; j < JCOLS; j++) { acc[j][0] = (f32x16)0.f; acc[j][1] = (f32x16)0.f; }

    // B staging source offsets (ushort units; + cgi*PXT*32 per chunk)
    int bgo[NBT];
    bool bgv[NBT];
    #pragma unroll
    for (int r = 0; r < NBT; r++) {
        int t = tid + 512 * r;
        bgv[r] = t < NBU;
        int tt = bgv[r] ? t : 0;
        int px = tt % NPX, kv = tt / NPX;
        int rr = px / SP, cc = px % SP;
        int Rc = R0 + rr; if (Rc > ROWMAX) Rc = ROWMAX;
        bgo[r] = (kv * PXT + Rc * SP + cc) * 8;
    }

    auto stage = [&](int cgi, int buf) {
        ushort* base = &lds[buf * PAIR];
        const ushort* asrc = wb + (size_t)cgi * 147456;
        #pragma unroll
        for (int r = 0; r < NAT; r++) {
            int u = tid + 512 * r;
            if (u < NAU) {
                int row = u >> 6;                // whole wave shares one row
                gload_lds16(asrc + ((size_t)(row * 512 + o0) + (u & 63)) * 8,
                            base + (r * 512 + nw * 64) * 8);
            }
        }
        const ushort* bsrc = Xp + (size_t)cgi * (PXT * 32);
        #pragma unroll
        for (int r = 0; r < NBT; r++)
            if (bgv[r])
                gload_lds16(bsrc + bgo[r], base + ASZ + (r * 512 + nw * 64) * 8);
    };

    stage(ks * CK, 0);
    for (int c = 0; c < CK; c++) {
        const int cur = c & 1;
        if (c + 1 < CK) {
            stage(ks * CK + c + 1, cur ^ 1);
            asm volatile("s_waitcnt vmcnt(%0)" :: "i"(NMIN) : "memory");
        } else {
            asm volatile("s_waitcnt vmcnt(0)" ::: "memory");
        }
        __builtin_amdgcn_s_barrier();
        __builtin_amdgcn_sched_barrier(0);
        const int bo = cur * PAIR;
        #pragma unroll
        for (int t = 0; t < 9; t++) {
            const int dpx = (t / 3) * SP + (t % 3);
            bf16x8 a0 = *(const bf16x8*)&lds[bo + ((t * 4 + kvw) * 64 + l31) * 8];
            bf16x8 a1 = *(const bf16x8*)&lds[bo + ((t * 4 + kvw) * 64 + 32 + l31) * 8];
            #pragma unroll
            for (int j = 0; j < JCOLS; j++) {
                bf16x8 bf = *(const bf16x8*)&lds[bo + ASZ + (kvw * NPX + pixbase[j] + dpx) * 8];
                acc[j][0] = __builtin_amdgcn_mfma_f32_32x32x16_bf16(a0, bf, acc[j][0], 0, 0, 0);
                acc[j][1] = __builtin_amdgcn_mfma_f32_32x32x16_bf16(a1, bf, acc[j][1], 0, 0, 0);
            }
        }
        __builtin_amdgcn_sched_barrier(0);
        __builtin_amdgcn_s_barrier();
    }

    // ---- cross-wave K reduction: sw=1 half spills, sw=0 half accumulates ----
    #pragma unroll
    for (int j = 0; j < JCOLS; j++)
        #pragma unroll
        for (int sub = 0; sub < 2; sub++)
            #pragma unroll
            for (int rq = 0; rq < 4; rq++)
                if (sw == 1) {
                    int sidx = (j * 2 + sub) * 4 + rq;
                    float4 v = make_float4(acc[j][sub][rq * 4 + 0], acc[j][sub][rq * 4 + 1],
                                           acc[j][sub][rq * 4 + 2], acc[j][sub][rq * 4 + 3]);
                    *(float4*)&lds[sidx * 2048 + (nww * 64 + lane) * 8] = v;
                }
    __syncthreads();
    if (sw == 1) return;
    #pragma unroll
    for (int j = 0; j < JCOLS; j++)
        #pragma unroll
        for (int sub = 0; sub < 2; sub++)
            #pragma unroll
            for (int rq = 0; rq < 4; rq++) {
                int sidx = (j * 2 + sub) * 4 + rq;
                float4 p = *(const float4*)&lds[sidx * 2048 + (nww * 64 + lane) * 8];
                acc[j][sub][rq * 4 + 0] += p.x;
                acc[j][sub][rq * 4 + 1] += p.y;
                acc[j][sub][rq * 4 + 2] += p.z;
                acc[j][sub][rq * 4 + 3] += p.w;
            }

    if constexpr (KS > 1) {
        #pragma unroll
        for (int j = 0; j < JCOLS; j++) {
            float* pb = Pp + (((size_t)(ks * N + nj[j])) << 9) + o0;
            #pragma unroll
            for (int sub = 0; sub < 2; sub++) {
                #pragma unroll
                for (int rq = 0; rq < 4; rq++) {
                    float4 v = make_float4(acc[j][sub][rq * 4 + 0], acc[j][sub][rq * 4 + 1],
                                           acc[j][sub][rq * 4 + 2], acc[j][sub][rq * 4 + 3]);
                    *(float4*)&pb[sub * 32 + 4 * hf + 8 * rq] = v;
                }
            }
        }
        return;
    }
    float ns = nstr[0];
    #pragma unroll
    for (int j = 0; j < JCOLS; j++) {
        int n = nj[j], b = n / P2, r = n % P2;
        float nv = nz[b * P2 + r];
        int y = r / S, x = r % S;
        size_t tbase = (size_t)n << 9;
        int gpx = (b * SP + y + 1) * SP + x + 1;
        #pragma unroll
        for (int sub = 0; sub < 2; sub++) {
            #pragma unroll
            for (int rq = 0; rq < 4; rq++) {
                int o = o0 + sub * 32 + 4 * hf + 8 * rq;
                float4 d4 = *(const float4*)&dm[b * 512 + o];
                float4 b4 = *(const float4*)&bias[o];
                float vv[4];
                #pragma unroll
                for (int ri = 0; ri < 4; ri++) {
                    float v = acc[j][sub][rq * 4 + ri] * (&d4.x)[ri] * CONV_SCALE
                              + ns * nv + (&b4.x)[ri];
                    vv[ri] = (v > 0.f ? v : 0.2f * v) * SQRT2F;
                }
                store4bf(T + tbase + o, vv[0], vv[1], vv[2], vv[3]);
                if (WUP) {
                    float4 s4 = *(const float4*)&snext[b * 512 + o];
                    store4bf(XU + ((size_t)(o >> 3) * PXT + gpx) * 8 + (o & 7),
                             vv[0] * s4.x, vv[1] * s4.y, vv[2] * s4.z, vv[3] * s4.w);
                }
            }
        }
    }
}

// ============ K-split combine + epilogue (dense layers l0, l2, l4) ==========
// XU written g-major [g][px][8] for the following up-conv's B staging.
template <int S, int KS, bool WUP>
__global__ void combine_dense(const float* __restrict__ Pp, const float* __restrict__ dm,
                              const float* __restrict__ nz, const float* __restrict__ nstr,
                              const float* __restrict__ bias, const float* __restrict__ snext,
                              ushort* __restrict__ T, ushort* __restrict__ XU) {
    constexpr int P2 = S * S, N = 8 * P2, SP = S + 2;
    constexpr int PXT = 8 * SP * SP;
    int gid = blockIdx.x * 256 + threadIdx.x;
    int n = gid >> 7, og = (gid & 127) << 2;
    float4 sm = make_float4(0.f, 0.f, 0.f, 0.f);
    #pragma unroll
    for (int k = 0; k < KS; k++) {
        float4 p = *(const float4*)&Pp[(((size_t)(k * N + n)) << 9) + og];
        sm.x += p.x; sm.y += p.y; sm.z += p.z; sm.w += p.w;
    }
    int b = n / P2, r = n % P2;
    float nsv = nstr[0] * nz[b * P2 + r];
    float4 d4 = *(const float4*)&dm[b * 512 + og];
    float4 b4 = *(const float4*)&bias[og];
    float vv[4];
    const float* sp = &sm.x;
    #pragma unroll
    for (int i = 0; i < 4; i++) {
        float v = sp[i] * (&d4.x)[i] * CONV_SCALE + nsv + (&b4.x)[i];
        vv[i] = (v > 0.f ? v : 0.2f * v) * SQRT2F;
    }
    store4bf(&T[((size_t)n << 9) + og], vv[0], vv[1], vv[2], vv[3]);
    if (WUP) {
        int y = r / S, x = r % S;
        int gpx = (b * SP + y + 1) * SP + x + 1;
        float4 s4 = *(const float4*)&snext[b * 512 + og];
        store4bf(&XU[((size_t)(og >> 3) * PXT + gpx) * 8 + (og & 7)],
                 vv[0] * s4.x, vv[1] * s4.y, vv[2] * s4.z, vv[3] * s4.w);
    }
}

// ===== up-conv v5 (4 parity classes, coalesced DMA + dbuf + counted vmcnt) ==
// Xp g-major [g][px][8]; U output g-major for blur.
template <int HIN, int NTILE, int WRW>
__global__ __launch_bounds__(256, 2) void conv_up5(
    const ushort* __restrict__ Xp, const ushort* __restrict__ wb,
    const float* __restrict__ dm, ushort* __restrict__ U) {
    constexpr int SPI = HIN + 2, SOUT = 2 * HIN + 1, SPO = SOUT + 2;
    constexpr int PXT = 8 * SPI * SPI;
    constexpr int PXTO = 8 * SPO * SPO;
    constexpr int JCOLS = NTILE / 128;
    constexpr int NPX = WRW * SPI;
    constexpr int ASZ = 4 * 4 * 64 * 8;          // 8192 us per chunk
    constexpr int BSZ = NPX * 32;
    constexpr int PAIR = ASZ + BSZ;
    constexpr int NBU = NPX * 4;
    constexpr int NBT = (NBU + 255) / 256;
    constexpr int ROWMAX = 8 * SPI - 1;
    constexpr int MINB = (NBU > 192) ? ((NBU - 192 + 255) / 256) : 0;
    constexpr int NMIN = 4 + MINB;               // A staged as uniform 4 slots
    __shared__ __align__(16) ushort lds[2 * PAIR];

    const int py = blockIdx.z >> 1, pxp = blockIdx.z & 1;
    const int GY = py ? HIN : HIN + 1, GX = pxp ? HIN : HIN + 1;
    const int GG = GY * GX, NCLS = 8 * GG;
    const int NTY = py ? 1 : 2, NTX = pxp ? 1 : 2, NT = NTY * NTX;
    const int n0 = blockIdx.y * NTILE;
    if (n0 >= NCLS) return;

    int taplist[4], toffs[4];
    {
        int k = 0;
        #pragma unroll
        for (int a2 = 0; a2 < 2; a2++) {
            if (a2 >= NTY) break;
            int dy = py ? 1 : a2 * 2;
            #pragma unroll
            for (int c2 = 0; c2 < 2; c2++) {
                if (c2 >= NTX) break;
                int dx = pxp ? 1 : c2 * 2;
                taplist[k] = dy * 3 + dx;
                toffs[k] = ((dy + py) >> 1) * SPI + ((dx + pxp) >> 1);  // px units
                k++;
            }
        }
        for (; k < 4; k++) { taplist[k] = 0; toffs[k] = 0; }
    }

    const int tid = threadIdx.x, lane = tid & 63, nw = tid >> 6;
    const int hf = lane >> 5, l31 = lane & 31;
    const int o0 = blockIdx.x * 64;
    const int R0 = (n0 / GG) * SPI + (n0 % GG) / GX;

    int pixbase[JCOLS], bj[JCOLS], gyj[JCOLS], gxj[JCOLS];
    bool validj[JCOLS];
    #pragma unroll
    for (int j = 0; j < JCOLS; j++) {
        int n = n0 + nw * (NTILE / 4) + j * 32 + l31;
        validj[j] = n < NCLS;
        int nc = validj[j] ? n : (NCLS - 1);
        int b = nc / GG, rem = nc % GG;
        int gy = rem / GX, gx = rem % GX;
        bj[j] = b; gyj[j] = gy; gxj[j] = gx;
        pixbase[j] = (b * SPI + gy - R0) * SPI + gx;  // px units
    }
    f32x16 acc[JCOLS][2];
    #pragma unroll
    for (int j = 0; j < JCOLS; j++) { acc[j][0] = (f32x16)0.f; acc[j][1] = (f32x16)0.f; }

    int bgo[NBT];
    bool bgv[NBT];
    #pragma unroll
    for (int r = 0; r < NBT; r++) {
        int t = tid + 256 * r;
        bgv[r] = t < NBU;
        int tt = bgv[r] ? t : 0;
        int px = tt % NPX, kv = tt / NPX;
        int rr = px / SPI, cc = px % SPI;
        int Rc = R0 + rr; if (Rc > ROWMAX) Rc = ROWMAX;
        bgo[r] = (kv * PXT + Rc * SPI + cc) * 8;
    }
    const int aoff = (nw * 512 + o0 + lane) * 8;
    int atap[4];
    #pragma unroll
    for (int r = 0; r < 4; r++) atap[r] = taplist[r] * 16384;

    auto stage = [&](int cgi, int buf) {
        ushort* dstA = &lds[buf * PAIR + nw * 512];
        ushort* dstB = &lds[buf * PAIR + ASZ + nw * 512];
        const ushort* asrc = wb + (size_t)cgi * 147456 + aoff;
        #pragma unroll
        for (int r = 0; r < 4; r++)   // uniform 4 A-slots (pad taps repeat tap0)
            gload_lds16(asrc + atap[r], dstA + r * 2048);
        const ushort* bsrc = Xp + (size_t)cgi * (PXT * 32);
        #pragma unroll
        for (int r = 0; r < NBT; r++)
            if (bgv[r])
                gload_lds16(bsrc + bgo[r], dstB + r * 2048);
    };

    stage(0, 0);
    for (int c = 0; c < 16; c++) {
        const int cur = c & 1;
        if (c + 1 < 16) {
            stage(c + 1, cur ^ 1);
            asm volatile("s_waitcnt vmcnt(%0)" :: "i"(NMIN) : "memory");
        } else {
            asm volatile("s_waitcnt vmcnt(0)" ::: "memory");
        }
        __builtin_amdgcn_s_barrier();
        __builtin_amdgcn_sched_barrier(0);
        const int bo = cur * PAIR;
        for (int tt = 0; tt < NT; ++tt) {
            const int dpx = toffs[tt];
            #pragma unroll
            for (int s = 0; s < 2; s++) {
                const int kv = s * 2 + hf;
                bf16x8 a0 = *(const bf16x8*)&lds[bo + ((tt * 4 + kv) * 64 + l31) * 8];
                bf16x8 a1 = *(const bf16x8*)&lds[bo + ((tt * 4 + kv) * 64 + 32 + l31) * 8];
                #pragma unroll
                for (int j = 0; j < JCOLS; j++) {
                    bf16x8 bf = *(const bf16x8*)&lds[bo + ASZ + (kv * NPX + pixbase[j] + dpx) * 8];
                    acc[j][0] = __builtin_amdgcn_mfma_f32_32x32x16_bf16(a0, bf, acc[j][0], 0, 0, 0);
                    acc[j][1] = __builtin_amdgcn_mfma_f32_32x32x16_bf16(a1, bf, acc[j][1], 0, 0, 0);
                }
            }
        }
        __builtin_amdgcn_sched_barrier(0);
        __builtin_amdgcn_s_barrier();
    }
    #pragma unroll
    for (int j = 0; j < JCOLS; j++) {
        if (!validj[j]) continue;
        int b = bj[j];
        int y = 2 * gyj[j] + py, x = 2 * gxj[j] + pxp;
        int gpx = (b * SPO + y + 1) * SPO + x + 1;
        #pragma unroll
        for (int sub = 0; sub < 2; sub++) {
            #pragma unroll
            for (int rq = 0; rq < 4; rq++) {
                int o = o0 + sub * 32 + 4 * hf + 8 * rq;
                float4 d4 = *(const float4*)&dm[b * 512 + o];
                float vv[4];
                #pragma unroll
                for (int ri = 0; ri < 4; ri++)
                    vv[ri] = acc[j][sub][rq * 4 + ri] * (&d4.x)[ri] * CONV_SCALE;
                store4bf(U + ((size_t)(o >> 3) * PXTO + gpx) * 8 + (o & 7),
                         vv[0], vv[1], vv[2], vv[3]);
            }
        }
    }
}

// ========= blur 4x4 + noise + bias + lrelu + style (g-major in/out) =========
template <int SIN>
__global__ void blur_px(const ushort* __restrict__ U, const float* __restrict__ nz,
                        const float* __restrict__ nstr, const float* __restrict__ bias,
                        const float* __restrict__ snext, ushort* __restrict__ X) {
    constexpr int O = SIN - 1, SPI = SIN + 2, SPO = O + 2;
    constexpr int PXTU = 8 * SPI * SPI;
    constexpr int PXTO = 8 * SPO * SPO;
    int gid = blockIdx.x * 256 + threadIdx.x;
    if (gid >= 8 * O * O * 64) return;
    int grp = gid & 63;
    int pxl = gid >> 6;
    int b = pxl / (O * O), r = pxl % (O * O), u = r / O, vcol = r % O;
    const float k1[4] = {0.25f, 0.75f, 0.75f, 0.25f};
    float acc[8];
    #pragma unroll
    for (int k = 0; k < 8; k++) acc[k] = 0.f;
    const ushort* Ug = U + (size_t)grp * PXTU * 8;
    #pragma unroll
    for (int a = 0; a < 4; a++) {
        int row = b * SPI + u + a;
        #pragma unroll
        for (int c = 0; c < 4; c++) {
            float w = k1[a] * k1[c];
            bf16x8 v = *(const bf16x8*)&Ug[(size_t)(row * SPI + vcol + c) * 8];
            #pragma unroll
            for (int k = 0; k < 8; k++) acc[k] += w * bf2f((ushort)v[k]);
        }
    }
    float nsv = nstr[0] * nz[b * O * O + r];
    float4 b0 = *(const float4*)&bias[grp * 8];
    float4 b1 = *(const float4*)&bias[grp * 8 + 4];
    float4 s0 = *(const float4*)&snext[b * 512 + grp * 8];
    float4 s1 = *(const float4*)&snext[b * 512 + grp * 8 + 4];
    union { ushort us[8]; bf16x8 v; } pk;
    #pragma unroll
    for (int k = 0; k < 8; k++) {
        float bk = (k < 4) ? (&b0.x)[k] : (&b1.x)[k - 4];
        float sk = (k < 4) ? (&s0.x)[k] : (&s1.x)[k - 4];
        float v = acc[k] + nsv + bk;
        v = (v > 0.f ? v : 0.2f * v) * SQRT2F;
        pk.us[k] = f2bf(v * sk);
    }
    *(bf16x8*)&X[((size_t)grp * PXTO + (b * SPO + u + 1) * SPO + vcol + 1) * 8] = pk.v;
}

// ======================== skip upsample (up=2, pad 2,1) =====================
template <int H>
__global__ void skipup_kernel(const float* __restrict__ skip, float* __restrict__ out) {
    constexpr int O = 2 * H;
    int idx = blockIdx.x * 256 + threadIdx.x;
    if (idx >= 8 * 3 * O * O) return;
    int px = idx % (O * O);
    int bc = idx / (O * O);
    int u = px / O, v = px % O;
    const float k1[4] = {0.25f, 0.75f, 0.75f, 0.25f};
    const float* src = skip + (size_t)bc * (H * H);
    float acc = 0.f;
    #pragma unroll
    for (int ty = 0; ty < 4; ty++) {
        int r = u + ty - 2;
        if (r < 0 || (r & 1) || (r >> 1) >= H) continue;
        float rsum = 0.f;
        #pragma unroll
        for (int tx = 0; tx < 4; tx++) {
            int cc = v + tx - 2;
            if (cc < 0 || (cc & 1) || (cc >> 1) >= H) continue;
            rsum += k1[tx] * src[(r >> 1) * H + (cc >> 1)];
        }
        acc += k1[ty] * rsum;
    }
    out[(size_t)bc * (O * O) + px] = acc;
}

// ============================ to_rgb (px-major T) ===========================
__global__ void torgb_px(const ushort* __restrict__ T, int P2,
                         const float* __restrict__ rgbw, const float* __restrict__ srgb,
                         const float* __restrict__ rbias, const float* __restrict__ skipup,
                         float* __restrict__ dst) {
    int b = blockIdx.x;
    int px = blockIdx.y * 4 + (threadIdx.x >> 6);
    int lane = threadIdx.x & 63;
    int c8 = lane * 8;
    bf16x8 v = *(const bf16x8*)&T[(((size_t)b * P2 + px) << 9) + c8];
    float4 sa = *(const float4*)&srgb[b * 512 + c8];
    float4 sb = *(const float4*)&srgb[b * 512 + c8 + 4];
    float xs[8];
    #pragma unroll
    for (int k = 0; k < 8; k++) {
        float sk = (k < 4) ? (&sa.x)[k] : (&sb.x)[k - 4];
        xs[k] = bf2f((ushort)v[k]) * sk;
    }
    float sums[3];
    #pragma unroll
    for (int c = 0; c < 3; c++) {
        float4 w0 = *(const float4*)&rgbw[c * 512 + c8];
        float4 w1 = *(const float4*)&rgbw[c * 512 + c8 + 4];
        float s = 0.f;
        #pragma unroll
        for (int k = 0; k < 8; k++) {
            float wk = (k < 4) ? (&w0.x)[k] : (&w1.x)[k - 4];
            s += xs[k] * wk;
        }
        #pragma unroll
        for (int off = 32; off > 0; off >>= 1) s += __shfl_xor(s, off, 64);
        sums[c] = s;
    }
    if (lane == 0) {
        #pragma unroll
        for (int c = 0; c < 3; c++) {
            float o = sums[c] * RGB_SCALE + rbias[c];
            if (skipup) o += skipup[((size_t)b * 3 + c) * P2 + px];
            dst[((size_t)b * 3 + c) * P2 + px] = o;
        }
    }
}

// ================================ launch ====================================

extern "C" void kernel_launch(void* const* d_in, const int* in_sizes, int n_in,
                              void* d_out, int out_size, void* d_ws, size_t ws_size,
                              hipStream_t stream) {
    const float* z      = (const float*)d_in[0];
    const float* mlp_w  = (const float*)d_in[1];
    const float* mlp_b  = (const float*)d_in[2];
    const float* cinp   = (const float*)d_in[3];
    const float* conv_w = (const float*)d_in[4];
    const float* cmw    = (const float*)d_in[5];
    const float* cmb    = (const float*)d_in[6];
    const float* cbias  = (const float*)d_in[7];
    const float* nstr   = (const float*)d_in[8];
    const float* rgbw   = (const float*)d_in[9];
    const float* rmw    = (const float*)d_in[10];
    const float* rmb    = (const float*)d_in[11];
    const float* rbias  = (const float*)d_in[12];
    float* out = (float*)d_out;
    float* ws = (float*)d_ws;

    // ---- workspace (float-slot offsets) ----
    float* wlatA = ws;                        // 4096
    float* wlatB = ws + 4096;                 // 4096
    float* sconv = ws + 8192;                 // 7*4096
    float* srgb  = ws + 36864;                // 4*4096
    float* dem   = ws + 53248;                // 7*4096
    float* noise = ws + 81920;                // 21632
    float* skipA = ws + 103552;               // 24576
    float* skipB = ws + 128128;               // 24576
    float* skipU = ws + 152704;               // 24576 -> 177280
    float* wsq7  = ws + 177280;               // 7*262144 = 1835008 -> 2012288
    ushort* wbuf7 = (ushort*)(ws + 2012288);  // 7*2359296 us = 8257536 f -> 10269824
    float* Ppart = ws + 10269824;             // 2097152 -> 12366976
    ushort* A1 = (ushort*)(ws + 12366976);    // 5017600 us -> f 14875776
    ushort* A2 = (ushort*)(ws + 14875776);    // 4734976 us -> f 17243264
    ushort* A3 = (ushort*)(ws + 17243264);    // 4194304 us -> f 19340416

    // arena aliases (lifetimes disjoint)
    ushort* X0p = A1;   // g-major 64*288*8
    ushort* T0  = A2;   // px-major 8*16*512
    ushort* XU1 = A3;   // g-major 64*288*8
    ushort* U1  = A1;   // g-major 64*968*8
    ushort* X2  = A2;   // g-major 64*800*8
    ushort* T2  = A3;   // px-major 8*64*512
    ushort* XU3 = A1;   // g-major 64*800*8
    ushort* U3  = A2;   // g-major 64*2888*8
    ushort* X4  = A1;   // g-major 64*2592*8
    ushort* T4  = A2;   // px-major 8*256*512
    ushort* XU5 = A3;   // g-major 64*2592*8
    ushort* U5  = A1;   // g-major 64*9800*8
    ushort* X6  = A2;   // g-major 64*9248*8
    ushort* T6  = A3;   // px-major 8*1024*512

    const size_t LWB = 2359296;  // us per layer in wbuf7

    // weights repack (all layers) + noise (independent of mapping)
    wbconv_all<<<896, 256, 0, stream>>>(conv_w, wbuf7, wsq7);
    noise_kernel<<<85, 256, 0, stream>>>(noise);

    // mapping network
    pixelnorm_kernel<<<8, 64, 0, stream>>>(z, wlatA);
    float* a = wlatA;
    float* bb = wlatB;
    for (int i = 0; i < 8; i++) {
        dot512_kernel<<<1024, 256, 0, stream>>>(a, mlp_w + (size_t)i * 262144,
                                                mlp_b + i * 512, bb, 4096,
                                                MAP_SCALE, 0.01f, 1);
        float* t = a; a = bb; bb = t;
    }
    dot512_kernel<<<7168, 256, 0, stream>>>(a, cmw, cmb, sconv, 7 * 4096, MOD_SCALE, 1.0f, 0);
    dot512_kernel<<<4096, 256, 0, stream>>>(a, rmw, rmb, srgb, 4 * 4096, MOD_SCALE, 1.0f, 0);
    demod_all<<<7168, 256, 0, stream>>>(wsq7, sconv, dem);
    prep0_kernel<<<72, 256, 0, stream>>>(cinp, sconv, X0p);

    // ---- layer 0 (dense 4x4, K-split 16 -> 128 blocks, single-chunk) ----
    conv_dense6<4, 128, 48, 16, false><<<dim3(8, 1, 16), 512, 0, stream>>>(
        X0p, wbuf7, nullptr, nullptr, nullptr, nullptr, nullptr,
        nullptr, nullptr, Ppart);
    hipMemsetAsync(XU1, 0, (size_t)8 * 36 * 512 * 2, stream);
    combine_dense<4, 16, true><<<64, 256, 0, stream>>>(
        Ppart, dem, noise, nstr, cbias, sconv + 4096, T0, XU1);
    torgb_px<<<dim3(8, 4), 256, 0, stream>>>(T0, 16, rgbw, srgb, rbias, nullptr, skipA);

    // ---- layer 1 (up 4->9, all classes) ----
    hipMemsetAsync(U1, 0, (size_t)8 * 121 * 512 * 2, stream);
    conv_up5<4, 128, 48><<<dim3(8, 2, 4), 256, 0, stream>>>(XU1, wbuf7 + LWB, dem + 4096, U1);
    hipMemsetAsync(X2, 0, (size_t)8 * 100 * 512 * 2, stream);
    blur_px<9><<<128, 256, 0, stream>>>(U1, noise + 128, nstr + 1, cbias + 512,
                                        sconv + 2 * 4096, X2);

    // ---- layer 2 (dense 8x8, K-split 8 -> 256 blocks) ----
    conv_dense6<8, 128, 20, 8, false><<<dim3(8, 4, 8), 512, 0, stream>>>(
        X2, wbuf7 + 2 * LWB, nullptr, nullptr, nullptr, nullptr, nullptr,
        nullptr, nullptr, Ppart);
    hipMemsetAsync(XU3, 0, (size_t)8 * 100 * 512 * 2, stream);
    combine_dense<8, 8, true><<<256, 256, 0, stream>>>(
        Ppart, dem + 2 * 4096, noise + 640, nstr + 2, cbias + 2 * 512,
        sconv + 3 * 4096, T2, XU3);
    skipup_kernel<4><<<6, 256, 0, stream>>>(skipA, skipU);
    torgb_px<<<dim3(8, 16), 256, 0, stream>>>(T2, 64, rgbw + 1536, srgb + 4096,
                                              rbias + 3, skipU, skipB);

    // ---- layer 3 (up 8->17, all classes) ----
    hipMemsetAsync(U3, 0, (size_t)8 * 361 * 512 * 2, stream);
    conv_up5<8, 128, 22><<<dim3(8, 6, 4), 256, 0, stream>>>(XU3, wbuf7 + 3 * LWB,
                                                            dem + 3 * 4096, U3);
    hipMemsetAsync(X4, 0, (size_t)8 * 324 * 512 * 2, stream);
    blur_px<17><<<512, 256, 0, stream>>>(U3, noise + 1152, nstr + 3, cbias + 3 * 512,
                                         sconv + 4 * 4096, X4);

    // ---- layer 4 (dense 16x16, NTILE=128, K-split 2 -> 256 blocks) ----
    conv_dense6<16, 128, 10, 2, false><<<dim3(8, 16, 2), 512, 0, stream>>>(
        X4, wbuf7 + 4 * LWB, nullptr, nullptr, nullptr, nullptr, nullptr,
        nullptr, nullptr, Ppart);
    hipMemsetAsync(XU5, 0, (size_t)8 * 324 * 512 * 2, stream);
    combine_dense<16, 2, true><<<1024, 256, 0, stream>>>(
        Ppart, dem + 4 * 4096, noise + 3200, nstr + 4, cbias + 4 * 512,
        sconv + 5 * 4096, T4, XU5);
    skipup_kernel<8><<<24, 256, 0, stream>>>(skipB, skipU);
    torgb_px<<<dim3(8, 64), 256, 0, stream>>>(T4, 256, rgbw + 2 * 1536, srgb + 2 * 4096,
                                              rbias + 6, skipU, skipA);

    // ---- layer 5 (up 16->33, all classes) ----
    hipMemsetAsync(U5, 0, (size_t)8 * 1225 * 512 * 2, stream);
    conv_up5<16, 256, 20><<<dim3(8, 10, 4), 256, 0, stream>>>(XU5, wbuf7 + 5 * LWB,
                                                              dem + 5 * 4096, U5);
    hipMemsetAsync(X6, 0, (size_t)8 * 1156 * 512 * 2, stream);
    blur_px<33><<<2048, 256, 0, stream>>>(U5, noise + 5248, nstr + 5, cbias + 5 * 512,
                                          sconv + 6 * 4096, X6);

    // ---- layer 6 (dense 32x32, NTILE=256 -> 256 blocks, 8-wave K-split) ----
    conv_dense6<32, 256, 10, 1, false><<<dim3(8, 32, 1), 512, 0, stream>>>(
        X6, wbuf7 + 6 * LWB, dem + 6 * 4096, noise + 13440, nstr + 6, cbias + 6 * 512,
        nullptr, T6, nullptr, nullptr);
    skipup_kernel<16><<<96, 256, 0, stream>>>(skipA, skipU);
    torgb_px<<<dim3(8, 256), 256, 0, stream>>>(T6, 1024, rgbw + 3 * 1536, srgb + 3 * 4096,
                                               rbias + 9, skipU, out);
}